// Round 5
// baseline (216.003 us; speedup 1.0000x reference)
//
#include <hip/hip_runtime.h>
#include <cstdint>

// Problem constants
#define BB 4
#define TT 2048      // TQ == TK
#define DD 512
#define HH 8
#define DH 64
#define NT (TT / 64) // KV tiles of 64
#define LOG2E 1.4426950408889634f

using bf16x8 = __attribute__((ext_vector_type(8))) __bf16;
using f32x4  = __attribute__((ext_vector_type(4))) float;
using us8    = __attribute__((ext_vector_type(8))) unsigned short;
using us4    = __attribute__((ext_vector_type(4))) unsigned short;
using u32x2  = __attribute__((ext_vector_type(2))) unsigned int;

typedef const __attribute__((address_space(1))) unsigned int* as1cp;
typedef __attribute__((address_space(3))) unsigned int* as3p;

__device__ __forceinline__ void gload16(const void* g, void* l) {
  __builtin_amdgcn_global_load_lds((as1cp)(uintptr_t)g,
                                   (as3p)(unsigned int)(uintptr_t)l, 16, 0, 0);
}

__device__ __forceinline__ unsigned short f2bf(float x) {
  unsigned int u = __float_as_uint(x);
  u += 0x7fffu + ((u >> 16) & 1u);
  return (unsigned short)(u >> 16);
}
__device__ __forceinline__ float bf2f(unsigned short u) {
  return __uint_as_float(((unsigned int)u) << 16);
}
__device__ __forceinline__ f32x4 MFMA(bf16x8 a, bf16x8 b, f32x4 c) {
  return __builtin_amdgcn_mfma_f32_16x16x32_bf16(a, b, c, 0, 0, 0);
}

#define WAITVM(N) asm volatile("s_waitcnt vmcnt(" #N ")" ::: "memory")
#define RAWBAR() asm volatile("s_barrier" ::: "memory")

// ---------------- 1. prep: convert inputs to bf16 + weight transpose ----------------
__global__ __launch_bounds__(256) void prep_kernel(const float4* __restrict__ q,
                                                   const float4* __restrict__ k,
                                                   us4* __restrict__ qb,
                                                   us4* __restrict__ kb,
                                                   const float* __restrict__ Wq,
                                                   const float* __restrict__ Wk,
                                                   const float* __restrict__ Wv,
                                                   unsigned short* __restrict__ Wt) {
  __shared__ float tile[32][33];
  int id = blockIdx.x;
  if (id < 4096) {
    size_t i = (size_t)id * 256 + threadIdx.x;
    float4 a = q[i];
    us4 o; o[0] = f2bf(a.x); o[1] = f2bf(a.y); o[2] = f2bf(a.z); o[3] = f2bf(a.w);
    qb[i] = o;
    float4 b = k[i];
    us4 p; p[0] = f2bf(b.x); p[1] = f2bf(b.y); p[2] = f2bf(b.z); p[3] = f2bf(b.w);
    kb[i] = p;
  } else {
    int id2 = id - 4096;
    int z = id2 >> 8, rem = id2 & 255;
    const float* W = (z == 0) ? Wq : (z == 1) ? Wk : Wv;
    int k0 = (rem & 15) * 32, n0 = (rem >> 4) * 32;
    int r = threadIdx.x >> 5, c = threadIdx.x & 31;
#pragma unroll
    for (int p = 0; p < 4; ++p)
      tile[r + p * 8][c] = W[(size_t)(k0 + r + p * 8) * DD + n0 + c];
    __syncthreads();
    unsigned short* o = Wt + (size_t)z * DD * DD;
#pragma unroll
    for (int p = 0; p < 4; ++p)
      o[(size_t)(n0 + r + p * 8) * DD + k0 + c] = f2bf(tile[c][r + p * 8]);
  }
}

// ---------------- 2. projection GEMM: out = relu(A @ W + b) [* 0.125*log2e for Q] ----------------
__global__ __launch_bounds__(256) void gemm_proj(const unsigned short* __restrict__ qb,
                                                 const unsigned short* __restrict__ kb,
                                                 const unsigned short* __restrict__ Wt,
                                                 const float* __restrict__ bq,
                                                 const float* __restrict__ bk,
                                                 const float* __restrict__ bv,
                                                 unsigned short* __restrict__ Qp,
                                                 unsigned short* __restrict__ Kp,
                                                 unsigned short* __restrict__ Vp) {
  int z = blockIdx.z;
  const unsigned short* A  = (z == 0) ? qb : kb;
  const unsigned short* Bt = Wt + (size_t)z * DD * DD;
  const float* bias = (z == 0) ? bq : (z == 1) ? bk : bv;
  unsigned short* out = (z == 0) ? Qp : (z == 1) ? Kp : Vp;
  const float osc = (z == 0) ? 0.125f * LOG2E : 1.0f;  // scores in log2 domain

  __shared__ __align__(16) unsigned short As[128 * 32];
  __shared__ __align__(16) unsigned short Bs[128 * 32];

  int mb = blockIdx.x * 128, nb = blockIdx.y * 128;
  int w = threadIdx.x >> 6, lane = threadIdx.x & 63;
  int l15 = lane & 15, lg = lane >> 4;
  int wr = (w >> 1) * 64, wc = (w & 1) * 64;

  f32x4 acc[4][4] = {};

  for (int kt = 0; kt < DD / 32; ++kt) {
    int kk = kt * 32;
    int t = threadIdx.x;
#pragma unroll
    for (int it = 0; it < 2; ++it) {
      int c = t + it * 256;
      gload16(A  + (size_t)(mb + (c >> 2)) * DD + kk + (c & 3) * 8, As + c * 8);
      gload16(Bt + (size_t)(nb + (c >> 2)) * DD + kk + (c & 3) * 8, Bs + c * 8);
    }
    __syncthreads();
    bf16x8 af[4], bf[4];
#pragma unroll
    for (int m = 0; m < 4; ++m)
      af[m] = *(const bf16x8*)&As[(wr + m * 16 + l15) * 32 + lg * 8];
#pragma unroll
    for (int n = 0; n < 4; ++n)
      bf[n] = *(const bf16x8*)&Bs[(wc + n * 16 + l15) * 32 + lg * 8];
#pragma unroll
    for (int m = 0; m < 4; ++m)
#pragma unroll
      for (int n = 0; n < 4; ++n)
        acc[m][n] = MFMA(af[m], bf[n], acc[m][n]);
    __syncthreads();
  }

#pragma unroll
  for (int m = 0; m < 4; ++m)
#pragma unroll
    for (int n = 0; n < 4; ++n)
#pragma unroll
      for (int i = 0; i < 4; ++i) {
        int row = mb + wr + m * 16 + lg * 4 + i;
        int col = nb + wc + n * 16 + l15;
        float v = acc[m][n][i] + bias[col];
        out[(size_t)row * DD + col] = f2bf(fmaxf(v, 0.f) * osc);
      }
}

// ---------------- 3. post-proj: V transpose + masks ----------------
__global__ __launch_bounds__(256) void post_proj(const unsigned short* __restrict__ Qp,
                                                 const unsigned short* __restrict__ Kp,
                                                 const unsigned short* __restrict__ Vp,
                                                 unsigned short* __restrict__ Vt,
                                                 float* __restrict__ qmask,
                                                 uint2* __restrict__ kbits) {
  __shared__ unsigned short tile[64][72];
  int id = blockIdx.x;
  if (id < 1024) {           // V transpose: Vp[B*TK, D] -> Vt[B, D, TK]
    int b = id >> 8, k0 = (id & 31) * 64, d0 = ((id >> 5) & 7) * 64;
    int t = threadIdx.x;
    int r = t >> 3, c8 = (t & 7) * 8;
#pragma unroll
    for (int p = 0; p < 2; ++p) {
      int row = r + p * 32;
      us8 v = *(const us8*)&Vp[(size_t)(b * TT + k0 + row) * DD + d0 + c8];
#pragma unroll
      for (int j = 0; j < 8; ++j) tile[row][c8 + j] = v[j];
    }
    __syncthreads();
#pragma unroll
    for (int p = 0; p < 2; ++p) {
      int dr = r + p * 32;
      us8 o;
#pragma unroll
      for (int j = 0; j < 8; ++j) o[j] = tile[c8 + j][dr];
      *(us8*)&Vt[((size_t)b * DD + d0 + dr) * TT + k0 + c8] = o;
    }
  } else {                   // masks
    int wid = (id - 1024) * 4 + (threadIdx.x >> 6);   // [0, 2048)
    int lane = threadIdx.x & 63;
    int side = wid >> 10;            // 0 = Q, 1 = K
    int rem = wid & 1023;
    int bh = rem >> 5, tl = rem & 31;
    int b = bh >> 3, h = bh & 7;
    const unsigned short* src =
        (side ? Kp : Qp) + ((size_t)(b * TT + tl * 64 + lane)) * DD + h * DH;
    float s = 0.f;
#pragma unroll
    for (int j = 0; j < 64; j += 8) {
      us8 v = *(const us8*)(src + j);
#pragma unroll
      for (int e = 0; e < 8; ++e) s += bf2f(v[e]);
    }
    if (side == 0) {
      qmask[(size_t)bh * TT + tl * 64 + lane] = (s > 0.f) ? 1.f : 0.f;
    } else {
      unsigned long long mb = __ballot(s > 0.f);
      if (lane == 0)
        kbits[bh * NT + tl] = make_uint2((unsigned int)mb, (unsigned int)(mb >> 32));
    }
  }
}

// ---------------- 4. flash attention ----------------
// 16 q-rows per wave (16x16x32 MFMA), 4 waves/block, grid 1024.
// S^T = mfma(K_perm, Q): lane(l15,lg) s[f][i] = score for q=l15,
// kpos = 32(f>>1) + 8lg + 4(f&1) + i  (K rows permuted so PV B-frags are
// direct per-lane concatenations: zero cross-lane ops in P packing).
// O^T = mfma(Vt, P): lane holds O[d = 16fd+4lg+i][q=l15] -> all state lane-local.
#define STAGE(tt, pbuf)                                                      \
  {                                                                          \
    int c0_ = threadIdx.x;                                                   \
    _Pragma("unroll")                                                        \
    for (int it_ = 0; it_ < 2; ++it_) {                                      \
      int c_ = c0_ + it_ * 256;                                              \
      int r_ = c_ >> 3, j_ = c_ & 7;                                         \
      int js_ = j_ ^ (r_ & 7);                                               \
      gload16(kg + (size_t)((tt) * 64 + r_) * DD + js_ * 8,                  \
              &KsBuf[pbuf][(size_t)c_ * 8]);                                 \
      gload16(vg + (size_t)r_ * TT + (tt) * 64 + js_ * 8,                    \
              &VsBuf[pbuf][(size_t)c_ * 8]);                                 \
    }                                                                        \
  }

__global__ __launch_bounds__(256) void attn_kernel(
    const unsigned short* __restrict__ Qp,
    const unsigned short* __restrict__ Kp,
    const unsigned short* __restrict__ Vt,
    const uint2* __restrict__ kbits,
    const float* __restrict__ qmask,
    float* __restrict__ O) {
  __shared__ __align__(16) unsigned short KsBuf[2][64 * 64];
  __shared__ __align__(16) unsigned short VsBuf[2][64 * 64];

  const int w = threadIdx.x >> 6;
  const int lane = threadIdx.x & 63;
  const int l15 = lane & 15, lg = lane >> 4;

  // XCD-bijective swizzle: 1024 blocks, each XCD gets 4 (b,h) x 32 q-tiles
  int flat = blockIdx.x;
  int wg = (flat & 7) * 128 + (flat >> 3);
  int qt = wg & 31, bh = wg >> 5;
  int h = bh & 7, b = bh >> 3;
  int q0 = qt * 64 + w * 16;

  // Q B-fragments: lane(l15,lg) holds Q[q0+l15][8lg .. +8] and [32+8lg ..]
  const unsigned short* qbase =
      Qp + ((size_t)(b * TT + q0 + l15)) * DD + h * DH + lg * 8;
  bf16x8 qf0 = *(const bf16x8*)(qbase);
  bf16x8 qf1 = *(const bf16x8*)(qbase + 32);

  const unsigned short* kg = Kp + ((size_t)b * TT) * DD + h * DH;
  const unsigned short* vg = Vt + ((size_t)(b * DD + h * DH)) * TT;
  const uint2* kb_ptr = kbits + (size_t)bh * NT;

  // permuted K-row base for A-frag row position p=l15: 8*(p>>2) + (p&3)
  const int krow_base = ((l15 & 12) << 1) | (l15 & 3);

  f32x4 oat[4] = {};
  float m_i = -1e30f, l_i = 0.f;

  STAGE(0, 0);

  for (int t = 0; t < NT; ++t) {
    int pb = t & 1;
    if (t + 1 < NT) {
      STAGE(t + 1, pb ^ 1);
      WAITVM(4);
    } else {
      WAITVM(0);
    }
    RAWBAR();

    const unsigned short* ksb = &KsBuf[pb][0];
    const unsigned short* vsb = &VsBuf[pb][0];

    // K A-frags (permuted rows) + QK^T
    f32x4 s[4];
    __builtin_amdgcn_s_setprio(1);
#pragma unroll
    for (int f = 0; f < 4; ++f) {
      int row = krow_base + ((f & 1) << 2) + ((f >> 1) << 5);
      int r7 = row & 7;
      bf16x8 k0 = *(const bf16x8*)&ksb[row * 64 + ((lg ^ r7) << 3)];
      bf16x8 k1 = *(const bf16x8*)&ksb[row * 64 + (((4 | lg) ^ r7) << 3)];
      f32x4 z = {};
      z = MFMA(k0, qf0, z);
      s[f] = MFMA(k1, qf1, z);
    }
    __builtin_amdgcn_s_setprio(0);

    // V A-frags (issue early; consumed after softmax)
    bf16x8 vf[4][2];
#pragma unroll
    for (int fd = 0; fd < 4; ++fd) {
      int row = 16 * fd + l15;
      int r7 = l15 & 7;
      vf[fd][0] = *(const bf16x8*)&vsb[row * 64 + ((lg ^ r7) << 3)];
      vf[fd][1] = *(const bf16x8*)&vsb[row * 64 + (((4 | lg) ^ r7) << 3)];
    }

    // key mask (fast path: all ones). kpos = 32(f>>1) + 8lg + 4(f&1) + i
    uint2 kw = kb_ptr[t];
    if ((kw.x & kw.y) != 0xffffffffu) {
#pragma unroll
      for (int f = 0; f < 4; ++f) {
        unsigned int word = (f >> 1) ? kw.y : kw.x;
        unsigned int nib = (word >> (8 * lg + 4 * (f & 1))) & 0xFu;
#pragma unroll
        for (int i = 0; i < 4; ++i)
          if (!((nib >> i) & 1)) s[f][i] = -1e30f;
      }
    }

    // row max: 16 local + cross-lane over the 4 lanes sharing l15
    float m0 = fmaxf(fmaxf(s[0][0], s[0][1]), fmaxf(s[0][2], s[0][3]));
    float m1 = fmaxf(fmaxf(s[1][0], s[1][1]), fmaxf(s[1][2], s[1][3]));
    float m2 = fmaxf(fmaxf(s[2][0], s[2][1]), fmaxf(s[2][2], s[2][3]));
    float m3 = fmaxf(fmaxf(s[3][0], s[3][1]), fmaxf(s[3][2], s[3][3]));
    float pm = fmaxf(fmaxf(m0, m1), fmaxf(m2, m3));
    pm = fmaxf(pm, __shfl_xor(pm, 16));
    u32x2 sw = __builtin_amdgcn_permlane32_swap(__float_as_uint(pm),
                                                __float_as_uint(pm), false, false);
    pm = fmaxf(__uint_as_float(sw[0]), __uint_as_float(sw[1]));

    // defer-max (log2 units): rescale only when max grew by > 12
    if (__any(pm > m_i + 12.f)) {
      float mn = fmaxf(m_i, pm);
      float al = exp2f(m_i - mn);
      m_i = mn;
      l_i *= al;
#pragma unroll
      for (int f = 0; f < 4; ++f)
#pragma unroll
        for (int i = 0; i < 4; ++i) oat[f][i] *= al;
    }

    // p = exp2(s - m) (clamped: guards any inf channel), row sum
    float a = 0.f;
#pragma unroll
    for (int f = 0; f < 4; ++f)
#pragma unroll
      for (int i = 0; i < 4; ++i) {
        float p = exp2f(fminf(s[f][i] - m_i, 30.f));
        s[f][i] = p;
        a += p;
      }
    a += __shfl_xor(a, 16);
    u32x2 sr = __builtin_amdgcn_permlane32_swap(__float_as_uint(a),
                                                __float_as_uint(a), false, false);
    a = __uint_as_float(sr[0]) + __uint_as_float(sr[1]);
    l_i += a;

    // P -> bf16 B-frags: direct per-lane concatenation (compiler emits cvt_pk)
    bf16x8 pb0v, pb1v;
#pragma unroll
    for (int f2 = 0; f2 < 2; ++f2)
#pragma unroll
      for (int i = 0; i < 4; ++i) {
        pb0v[f2 * 4 + i] = (__bf16)s[f2][i];
        pb1v[f2 * 4 + i] = (__bf16)s[2 + f2][i];
      }

    // O^T += Vt . P
    __builtin_amdgcn_s_setprio(1);
#pragma unroll
    for (int fd = 0; fd < 4; ++fd) {
      oat[fd] = MFMA(vf[fd][0], pb0v, oat[fd]);
      oat[fd] = MFMA(vf[fd][1], pb1v, oat[fd]);
    }
    __builtin_amdgcn_s_setprio(0);

    if (t + 1 < NT) RAWBAR();
  }

  // epilogue: lane(l15,lg) holds O[d = 16fd + 4lg + i][q = l15]
  float qm = qmask[(size_t)bh * TT + q0 + l15];
  float sc = qm / fmaxf(l_i, 1e-37f);
  float* ob = O + ((size_t)(b * TT + q0 + l15)) * DD + h * DH + 4 * lg;
#pragma unroll
  for (int fd = 0; fd < 4; ++fd) {
    float4 v = make_float4(oat[fd][0] * sc, oat[fd][1] * sc,
                           oat[fd][2] * sc, oat[fd][3] * sc);
    *(float4*)(ob + 16 * fd) = v;
  }
}

// ---------------- 5. residual + LayerNorm ----------------
__global__ __launch_bounds__(256) void ln_kernel(const float* __restrict__ O,
                                                 const float* __restrict__ qin,
                                                 const float* __restrict__ gamma,
                                                 const float* __restrict__ beta,
                                                 float* __restrict__ out) {
  int row = blockIdx.x * 4 + (threadIdx.x >> 6);
  int lane = threadIdx.x & 63;
  size_t base = (size_t)row * DD + lane * 8;
  const float4* o4 = (const float4*)(O + base);
  const float4* q4 = (const float4*)(qin + base);
  float4 a = o4[0], b2 = o4[1], c = q4[0], d2 = q4[1];
  float v[8];
  v[0] = a.x + c.x; v[1] = a.y + c.y; v[2] = a.z + c.z; v[3] = a.w + c.w;
  v[4] = b2.x + d2.x; v[5] = b2.y + d2.y; v[6] = b2.z + d2.z; v[7] = b2.w + d2.w;
  float s = 0.f, s2 = 0.f;
#pragma unroll
  for (int j = 0; j < 8; ++j) { s += v[j]; s2 += v[j] * v[j]; }
#pragma unroll
  for (int xm = 1; xm < 64; xm <<= 1) {
    s += __shfl_xor(s, xm);
    s2 += __shfl_xor(s2, xm);
  }
  float mu = s * (1.0f / DD);
  float var = s2 * (1.0f / DD) - mu * mu;
  float rs = rsqrtf(var + 1e-3f);
  const float* g = gamma + lane * 8;
  const float* bb = beta + lane * 8;
  float* ob = out + base;
#pragma unroll
  for (int j = 0; j < 8; ++j) ob[j] = (v[j] - mu) * rs * g[j] + bb[j];
}

// ---------------- launch ----------------
extern "C" void kernel_launch(void* const* d_in, const int* in_sizes, int n_in,
                              void* d_out, int out_size, void* d_ws, size_t ws_size,
                              hipStream_t stream) {
  (void)in_sizes; (void)n_in; (void)out_size; (void)ws_size;
  const float* queries = (const float*)d_in[0];
  const float* keys_in = (const float*)d_in[1];
  const float* Wq = (const float*)d_in[2];
  const float* bq = (const float*)d_in[3];
  const float* Wk = (const float*)d_in[4];
  const float* bk = (const float*)d_in[5];
  const float* Wv = (const float*)d_in[6];
  const float* bv = (const float*)d_in[7];
  const float* gamma = (const float*)d_in[8];
  const float* beta  = (const float*)d_in[9];
  float* out = (float*)d_out;

  char* ws = (char*)d_ws;
  unsigned short* qb = (unsigned short*)(ws);
  unsigned short* kb = (unsigned short*)(ws + (8ull << 20));
  float*          O  = (float*)(ws);               // aliases qb/kb after gemm
  unsigned short* Qp = (unsigned short*)(ws + (16ull << 20));
  unsigned short* Kp = (unsigned short*)(ws + (24ull << 20));
  unsigned short* Vp = (unsigned short*)(ws + (32ull << 20));
  unsigned short* Vt = (unsigned short*)(ws + (40ull << 20));
  unsigned short* Wt = (unsigned short*)(ws + (48ull << 20));
  float* qmaskp = (float*)(ws + (50ull << 20));
  uint2* kbitsp = (uint2*)(ws + (50ull << 20) + (512ull << 10));

  prep_kernel<<<4864, 256, 0, stream>>>((const float4*)queries, (const float4*)keys_in,
                                        (us4*)qb, (us4*)kb, Wq, Wk, Wv, Wt);
  gemm_proj<<<dim3(64, 4, 3), 256, 0, stream>>>(qb, kb, Wt, bq, bk, bv, Qp, Kp, Vp);
  post_proj<<<1536, 256, 0, stream>>>(Qp, Kp, Vp, Vt, qmaskp, kbitsp);
  attn_kernel<<<1024, 256, 0, stream>>>(Qp, Kp, Vt, kbitsp, qmaskp, O);
  ln_kernel<<<2048, 256, 0, stream>>>(O, queries, gamma, beta, out);
}

// Round 6
// 207.082 us; speedup vs baseline: 1.0431x; 1.0431x over previous
//
#include <hip/hip_runtime.h>
#include <cstdint>

// Problem constants
#define BB 4
#define TT 2048      // TQ == TK
#define DD 512
#define HH 8
#define DH 64
#define NT (TT / 64) // KV tiles of 64
#define LOG2E 1.4426950408889634f

using bf16x8 = __attribute__((ext_vector_type(8))) __bf16;
using f32x4  = __attribute__((ext_vector_type(4))) float;
using f32x16 = __attribute__((ext_vector_type(16))) float;
using us8    = __attribute__((ext_vector_type(8))) unsigned short;
using us4    = __attribute__((ext_vector_type(4))) unsigned short;
using u32x2  = __attribute__((ext_vector_type(2))) unsigned int;

typedef const __attribute__((address_space(1))) unsigned int* as1cp;
typedef __attribute__((address_space(3))) unsigned int* as3p;

__device__ __forceinline__ void gload16(const void* g, void* l) {
  __builtin_amdgcn_global_load_lds((as1cp)(uintptr_t)g,
                                   (as3p)(unsigned int)(uintptr_t)l, 16, 0, 0);
}

__device__ __forceinline__ unsigned short f2bf(float x) {
  unsigned int u = __float_as_uint(x);
  u += 0x7fffu + ((u >> 16) & 1u);
  return (unsigned short)(u >> 16);
}
__device__ __forceinline__ float bf2f(unsigned short u) {
  return __uint_as_float(((unsigned int)u) << 16);
}
__device__ __forceinline__ f32x4 MFMA(bf16x8 a, bf16x8 b, f32x4 c) {
  return __builtin_amdgcn_mfma_f32_16x16x32_bf16(a, b, c, 0, 0, 0);
}
__device__ __forceinline__ f32x16 MFMA32(bf16x8 a, bf16x8 b, f32x16 c) {
  return __builtin_amdgcn_mfma_f32_32x32x16_bf16(a, b, c, 0, 0, 0);
}

#define WAITVM(N) asm volatile("s_waitcnt vmcnt(" #N ")" ::: "memory")
#define RAWBAR() asm volatile("s_barrier" ::: "memory")

// ---------------- 1. prep: convert inputs to bf16 + weight transpose ----------------
__global__ __launch_bounds__(256) void prep_kernel(const float4* __restrict__ q,
                                                   const float4* __restrict__ k,
                                                   us4* __restrict__ qb,
                                                   us4* __restrict__ kb,
                                                   const float* __restrict__ Wq,
                                                   const float* __restrict__ Wk,
                                                   const float* __restrict__ Wv,
                                                   unsigned short* __restrict__ Wt) {
  __shared__ float tile[32][33];
  int id = blockIdx.x;
  if (id < 4096) {
    size_t i = (size_t)id * 256 + threadIdx.x;
    float4 a = q[i];
    us4 o; o[0] = f2bf(a.x); o[1] = f2bf(a.y); o[2] = f2bf(a.z); o[3] = f2bf(a.w);
    qb[i] = o;
    float4 b = k[i];
    us4 p; p[0] = f2bf(b.x); p[1] = f2bf(b.y); p[2] = f2bf(b.z); p[3] = f2bf(b.w);
    kb[i] = p;
  } else {
    int id2 = id - 4096;
    int z = id2 >> 8, rem = id2 & 255;
    const float* W = (z == 0) ? Wq : (z == 1) ? Wk : Wv;
    int k0 = (rem & 15) * 32, n0 = (rem >> 4) * 32;
    int r = threadIdx.x >> 5, c = threadIdx.x & 31;
#pragma unroll
    for (int p = 0; p < 4; ++p)
      tile[r + p * 8][c] = W[(size_t)(k0 + r + p * 8) * DD + n0 + c];
    __syncthreads();
    unsigned short* o = Wt + (size_t)z * DD * DD;
#pragma unroll
    for (int p = 0; p < 4; ++p)
      o[(size_t)(n0 + r + p * 8) * DD + k0 + c] = f2bf(tile[c][r + p * 8]);
  }
}

// ---------------- 2. projection GEMM: out = relu(A @ W + b) [* 0.125*log2e for Q] ----------------
__global__ __launch_bounds__(256) void gemm_proj(const unsigned short* __restrict__ qb,
                                                 const unsigned short* __restrict__ kb,
                                                 const unsigned short* __restrict__ Wt,
                                                 const float* __restrict__ bq,
                                                 const float* __restrict__ bk,
                                                 const float* __restrict__ bv,
                                                 unsigned short* __restrict__ Qp,
                                                 unsigned short* __restrict__ Kp,
                                                 unsigned short* __restrict__ Vp) {
  int z = blockIdx.z;
  const unsigned short* A  = (z == 0) ? qb : kb;
  const unsigned short* Bt = Wt + (size_t)z * DD * DD;
  const float* bias = (z == 0) ? bq : (z == 1) ? bk : bv;
  unsigned short* out = (z == 0) ? Qp : (z == 1) ? Kp : Vp;
  const float osc = (z == 0) ? 0.125f * LOG2E : 1.0f;  // scores in log2 domain

  __shared__ __align__(16) unsigned short As[128 * 32];
  __shared__ __align__(16) unsigned short Bs[128 * 32];

  int mb = blockIdx.x * 128, nb = blockIdx.y * 128;
  int w = threadIdx.x >> 6, lane = threadIdx.x & 63;
  int l15 = lane & 15, lg = lane >> 4;
  int wr = (w >> 1) * 64, wc = (w & 1) * 64;

  f32x4 acc[4][4] = {};

  for (int kt = 0; kt < DD / 32; ++kt) {
    int kk = kt * 32;
    int t = threadIdx.x;
#pragma unroll
    for (int it = 0; it < 2; ++it) {
      int c = t + it * 256;
      gload16(A  + (size_t)(mb + (c >> 2)) * DD + kk + (c & 3) * 8, As + c * 8);
      gload16(Bt + (size_t)(nb + (c >> 2)) * DD + kk + (c & 3) * 8, Bs + c * 8);
    }
    __syncthreads();
    bf16x8 af[4], bf[4];
#pragma unroll
    for (int m = 0; m < 4; ++m)
      af[m] = *(const bf16x8*)&As[(wr + m * 16 + l15) * 32 + lg * 8];
#pragma unroll
    for (int n = 0; n < 4; ++n)
      bf[n] = *(const bf16x8*)&Bs[(wc + n * 16 + l15) * 32 + lg * 8];
#pragma unroll
    for (int m = 0; m < 4; ++m)
#pragma unroll
      for (int n = 0; n < 4; ++n)
        acc[m][n] = MFMA(af[m], bf[n], acc[m][n]);
    __syncthreads();
  }

#pragma unroll
  for (int m = 0; m < 4; ++m)
#pragma unroll
    for (int n = 0; n < 4; ++n)
#pragma unroll
      for (int i = 0; i < 4; ++i) {
        int row = mb + wr + m * 16 + lg * 4 + i;
        int col = nb + wc + n * 16 + l15;
        float v = acc[m][n][i] + bias[col];
        out[(size_t)row * DD + col] = f2bf(fmaxf(v, 0.f) * osc);
      }
}

// ---------------- 3. post-proj: V transpose + masks ----------------
__global__ __launch_bounds__(256) void post_proj(const unsigned short* __restrict__ Qp,
                                                 const unsigned short* __restrict__ Kp,
                                                 const unsigned short* __restrict__ Vp,
                                                 unsigned short* __restrict__ Vt,
                                                 float* __restrict__ qmask,
                                                 uint2* __restrict__ kbits) {
  __shared__ unsigned short tile[64][72];
  int id = blockIdx.x;
  if (id < 1024) {           // V transpose: Vp[B*TK, D] -> Vt[B, D, TK]
    int b = id >> 8, k0 = (id & 31) * 64, d0 = ((id >> 5) & 7) * 64;
    int t = threadIdx.x;
    int r = t >> 3, c8 = (t & 7) * 8;
#pragma unroll
    for (int p = 0; p < 2; ++p) {
      int row = r + p * 32;
      us8 v = *(const us8*)&Vp[(size_t)(b * TT + k0 + row) * DD + d0 + c8];
#pragma unroll
      for (int j = 0; j < 8; ++j) tile[row][c8 + j] = v[j];
    }
    __syncthreads();
#pragma unroll
    for (int p = 0; p < 2; ++p) {
      int dr = r + p * 32;
      us8 o;
#pragma unroll
      for (int j = 0; j < 8; ++j) o[j] = tile[c8 + j][dr];
      *(us8*)&Vt[((size_t)b * DD + d0 + dr) * TT + k0 + c8] = o;
    }
  } else {                   // masks
    int wid = (id - 1024) * 4 + (threadIdx.x >> 6);   // [0, 2048)
    int lane = threadIdx.x & 63;
    int side = wid >> 10;            // 0 = Q, 1 = K
    int rem = wid & 1023;
    int bh = rem >> 5, tl = rem & 31;
    int b = bh >> 3, h = bh & 7;
    const unsigned short* src =
        (side ? Kp : Qp) + ((size_t)(b * TT + tl * 64 + lane)) * DD + h * DH;
    float s = 0.f;
#pragma unroll
    for (int j = 0; j < 64; j += 8) {
      us8 v = *(const us8*)(src + j);
#pragma unroll
      for (int e = 0; e < 8; ++e) s += bf2f(v[e]);
    }
    if (side == 0) {
      qmask[(size_t)bh * TT + tl * 64 + lane] = (s > 0.f) ? 1.f : 0.f;
    } else {
      unsigned long long mb = __ballot(s > 0.f);
      if (lane == 0)
        kbits[bh * NT + tl] = make_uint2((unsigned int)mb, (unsigned int)(mb >> 32));
    }
  }
}

// ---------------- 4. flash attention (K-split x2, 32q/wave, MFMA32, K bit-swap perm) ----------------
// Per wave: 32 q-rows. S^T = MFMA32(K_frag, Q_frag); K rows staged with bits 2,3
// of kpos swapped, so reg r of sN holds score for actual kpos
//   32N + 16(r>>3) + 8*h2 + (r&7)
// which is EXACTLY the PV B-fragment order: pack = plain bf16 casts, no cross-lane.
// O^T = MFMA32(Vt_frag, P_frag): col stays q -> m/l/alpha all lane-local.
// Each block does 16 of 32 KV tiles (K-split); writes unnormalized bf16 O^T + (m,l).
#define STAGE(tt, pbuf)                                                      \
  {                                                                          \
    int c0_ = threadIdx.x;                                                   \
    _Pragma("unroll")                                                        \
    for (int it_ = 0; it_ < 2; ++it_) {                                      \
      int c_ = c0_ + it_ * 256;                                              \
      int r_ = c_ >> 3, j_ = c_ & 7;                                         \
      int js_ = j_ ^ (r_ & 7);                                               \
      int kr_ = (r_ & ~12) | ((r_ & 4) << 1) | ((r_ & 8) >> 1);              \
      gload16(kg + (size_t)((tt) * 64 + kr_) * DD + js_ * 8,                 \
              &KsBuf[pbuf][(size_t)c_ * 8]);                                 \
      gload16(vg + (size_t)r_ * TT + (tt) * 64 + js_ * 8,                    \
              &VsBuf[pbuf][(size_t)c_ * 8]);                                 \
    }                                                                        \
  }

__global__ __launch_bounds__(256) void attn_kernel(
    const unsigned short* __restrict__ Qp,
    const unsigned short* __restrict__ Kp,
    const unsigned short* __restrict__ Vt,
    const uint2* __restrict__ kbits,
    unsigned short* __restrict__ Opart,   // [2][32][TT][64] bf16, unnormalized O^T
    float2* __restrict__ ml) {            // [2][32][TT] (m, l)
  __shared__ __align__(16) unsigned short KsBuf[2][64 * 64];
  __shared__ __align__(16) unsigned short VsBuf[2][64 * 64];

  const int w = threadIdx.x >> 6;
  const int lane = threadIdx.x & 63;
  const int l31 = lane & 31, h2 = lane >> 5;

  // XCD-bijective swizzle: 1024 blocks; XCD x gets wg in [128x,128x+128)
  // wg bits: [bh(5)][qt(4)][s(1)] -> 4 (b,h) per XCD (K/V 4MB = one L2)
  int flat = blockIdx.x;
  int wg = (flat & 7) * 128 + (flat >> 3);
  int s = wg & 1, qt = (wg >> 1) & 15, bh = wg >> 5;
  int h = bh & 7, b = bh >> 3;
  int q0 = qt * 128 + w * 32;

  const unsigned short* qbase =
      Qp + ((size_t)(b * TT + q0 + l31)) * DD + h * DH + h2 * 8;
  bf16x8 qf[4];
#pragma unroll
  for (int kd = 0; kd < 4; ++kd) qf[kd] = *(const bf16x8*)(qbase + kd * 16);

  const unsigned short* kg = Kp + ((size_t)b * TT) * DD + h * DH;
  const unsigned short* vg = Vt + ((size_t)(b * DD + h * DH)) * TT;
  const uint2* kb_ptr = kbits + (size_t)bh * NT;

  f32x16 oat0 = {}, oat1 = {};
  float m_i = -1e30f, l_i = 0.f;

  const int t0 = s * 16, t1 = t0 + 16;
  STAGE(t0, 0);

  for (int t = t0; t < t1; ++t) {
    int pb = t & 1;
    if (t + 1 < t1) {
      STAGE(t + 1, pb ^ 1);
      WAITVM(4);
    } else {
      WAITVM(0);
    }
    RAWBAR();

    const unsigned short* ksb = &KsBuf[pb][0];
    const unsigned short* vsb = &VsBuf[pb][0];

    // K A-frags (label rows l31 / 32+l31), QK^T
    bf16x8 kf0[4], kf1[4];
#pragma unroll
    for (int kd = 0; kd < 4; ++kd) {
      int j = kd * 2 + h2;
      int x = (j ^ (l31 & 7)) << 3;
      kf0[kd] = *(const bf16x8*)&ksb[l31 * 64 + x];
      kf1[kd] = *(const bf16x8*)&ksb[(32 + l31) * 64 + x];
    }
    f32x16 s0 = {}, s1 = {};
    __builtin_amdgcn_s_setprio(1);
#pragma unroll
    for (int kd = 0; kd < 4; ++kd) s0 = MFMA32(kf0[kd], qf[kd], s0);
#pragma unroll
    for (int kd = 0; kd < 4; ++kd) s1 = MFMA32(kf1[kd], qf[kd], s1);
    __builtin_amdgcn_s_setprio(0);

    // key mask (fast path: all ones). actual kpos(reg r, sN) = 32N+16(r>>3)+8h2+(r&7)
    uint2 kw = kb_ptr[t];
    if ((kw.x & kw.y) != 0xffffffffu) {
#pragma unroll
      for (int r = 0; r < 16; ++r) {
        int sh = ((r >> 3) << 4) + (h2 << 3) + (r & 7);
        if (!((kw.x >> sh) & 1)) s0[r] = -1e30f;
        if (!((kw.y >> sh) & 1)) s1[r] = -1e30f;
      }
    }

    // row max over own 32, then cross-half (h2 pair) combine
    float x0 = fmaxf(fmaxf(fmaxf(s0[0], s0[1]), fmaxf(s0[2], s0[3])),
                     fmaxf(fmaxf(s0[4], s0[5]), fmaxf(s0[6], s0[7])));
    float x1 = fmaxf(fmaxf(fmaxf(s0[8], s0[9]), fmaxf(s0[10], s0[11])),
                     fmaxf(fmaxf(s0[12], s0[13]), fmaxf(s0[14], s0[15])));
    float x2 = fmaxf(fmaxf(fmaxf(s1[0], s1[1]), fmaxf(s1[2], s1[3])),
                     fmaxf(fmaxf(s1[4], s1[5]), fmaxf(s1[6], s1[7])));
    float x3 = fmaxf(fmaxf(fmaxf(s1[8], s1[9]), fmaxf(s1[10], s1[11])),
                     fmaxf(fmaxf(s1[12], s1[13]), fmaxf(s1[14], s1[15])));
    float pm = fmaxf(fmaxf(x0, x1), fmaxf(x2, x3));
    u32x2 sw = __builtin_amdgcn_permlane32_swap(__float_as_uint(pm),
                                                __float_as_uint(pm), false, false);
    pm = fmaxf(__uint_as_float(sw[0]), __uint_as_float(sw[1]));

    // defer-max (log2 units)
    if (__any(pm > m_i + 12.f)) {
      float mn = fmaxf(m_i, pm);
      float al = exp2f(m_i - mn);
      m_i = mn;
      l_i *= al;
#pragma unroll
      for (int r = 0; r < 16; ++r) { oat0[r] *= al; oat1[r] *= al; }
    }

    // p = exp2(s - m) (clamped), row sum (4 accumulators)
    float a0 = 0.f, a1 = 0.f, a2 = 0.f, a3 = 0.f;
#pragma unroll
    for (int r = 0; r < 8; ++r)  { float p = exp2f(fminf(s0[r] - m_i, 30.f)); s0[r] = p; a0 += p; }
#pragma unroll
    for (int r = 8; r < 16; ++r) { float p = exp2f(fminf(s0[r] - m_i, 30.f)); s0[r] = p; a1 += p; }
#pragma unroll
    for (int r = 0; r < 8; ++r)  { float p = exp2f(fminf(s1[r] - m_i, 30.f)); s1[r] = p; a2 += p; }
#pragma unroll
    for (int r = 8; r < 16; ++r) { float p = exp2f(fminf(s1[r] - m_i, 30.f)); s1[r] = p; a3 += p; }
    float rs = (a0 + a1) + (a2 + a3);
    u32x2 sr = __builtin_amdgcn_permlane32_swap(__float_as_uint(rs),
                                                __float_as_uint(rs), false, false);
    rs = __uint_as_float(sr[0]) + __uint_as_float(sr[1]);
    l_i += rs;

    // V A-frags
    bf16x8 vf0[4], vf1[4];
#pragma unroll
    for (int ks = 0; ks < 4; ++ks) {
      int j = ks * 2 + h2;
      int x = (j ^ (l31 & 7)) << 3;
      vf0[ks] = *(const bf16x8*)&vsb[l31 * 64 + x];
      vf1[ks] = *(const bf16x8*)&vsb[(32 + l31) * 64 + x];
    }

    // P -> bf16 B-frags: direct per-lane concatenation (perm makes order exact)
    bf16x8 pbf[4];
#pragma unroll
    for (int j = 0; j < 8; ++j) {
      pbf[0][j] = (__bf16)s0[j];
      pbf[1][j] = (__bf16)s0[8 + j];
      pbf[2][j] = (__bf16)s1[j];
      pbf[3][j] = (__bf16)s1[8 + j];
    }

    // O^T += Vt . P
    __builtin_amdgcn_s_setprio(1);
#pragma unroll
    for (int ks = 0; ks < 4; ++ks) {
      oat0 = MFMA32(vf0[ks], pbf[ks], oat0);
      oat1 = MFMA32(vf1[ks], pbf[ks], oat1);
    }
    __builtin_amdgcn_s_setprio(0);

    if (t + 1 < t1) RAWBAR();
  }

  // epilogue: write (m,l) + unnormalized bf16 O^T partial.
  // lane(l31,h2): oat0 reg r -> d = (r&3)+8*(r>>2)+4*h2 ; oat1 -> d+32. q = q0+l31.
  if (h2 == 0)
    ml[((size_t)s * 32 + bh) * TT + q0 + l31] = make_float2(m_i, l_i);
  unsigned short* op = Opart + (size_t)s * (32ull * TT * 64) +
                       ((size_t)bh * TT + q0 + l31) * 64;
#pragma unroll
  for (int e = 0; e < 8; ++e) {
    int r = e * 2;
    int d = (r & 3) + 8 * (r >> 2) + 4 * h2;
    unsigned int w0 = f2bf(oat0[r]) | ((unsigned int)f2bf(oat0[r + 1]) << 16);
    *(unsigned int*)(op + d) = w0;
    unsigned int w1 = f2bf(oat1[r]) | ((unsigned int)f2bf(oat1[r + 1]) << 16);
    *(unsigned int*)(op + 32 + d) = w1;
  }
}

// ---------------- 5. merge partials + qmask + residual + LayerNorm ----------------
__global__ __launch_bounds__(256) void ln_merge(const unsigned short* __restrict__ Opart,
                                                const float2* __restrict__ ml,
                                                const float* __restrict__ qmask,
                                                const float* __restrict__ qin,
                                                const float* __restrict__ gamma,
                                                const float* __restrict__ beta,
                                                float* __restrict__ out) {
  int row = blockIdx.x * 4 + (threadIdx.x >> 6);   // [0, B*TT)
  int j = threadIdx.x & 63;
  int b = row >> 11, q = row & (TT - 1);
  int h = j >> 3, bh = b * 8 + h;
  const size_t SSTR = 32ull * TT * 64;
  size_t pidx = ((size_t)bh * TT + q) * 64 + (size_t)(j & 7) * 8;
  us8 o0 = *(const us8*)(Opart + pidx);
  us8 o1 = *(const us8*)(Opart + SSTR + pidx);
  float2 ma = ml[(size_t)bh * TT + q];
  float2 mb = ml[32ull * TT + (size_t)bh * TT + q];
  float M = fmaxf(ma.x, mb.x);
  float w0 = exp2f(ma.x - M), w1 = exp2f(mb.x - M);
  float l = ma.y * w0 + mb.y * w1;
  float qm = qmask[(size_t)bh * TT + q];
  float sc = qm / fmaxf(l, 1e-30f);

  size_t base = (size_t)row * DD + (size_t)j * 8;
  const float4* q4 = (const float4*)(qin + base);
  float4 c = q4[0], d2 = q4[1];
  float qv[8] = {c.x, c.y, c.z, c.w, d2.x, d2.y, d2.z, d2.w};
  float v[8];
#pragma unroll
  for (int e = 0; e < 8; ++e)
    v[e] = (bf2f(o0[e]) * w0 + bf2f(o1[e]) * w1) * sc + qv[e];

  float s = 0.f, s2 = 0.f;
#pragma unroll
  for (int e = 0; e < 8; ++e) { s += v[e]; s2 += v[e] * v[e]; }
#pragma unroll
  for (int xm = 1; xm < 64; xm <<= 1) {
    s += __shfl_xor(s, xm);
    s2 += __shfl_xor(s2, xm);
  }
  float mu = s * (1.0f / DD);
  float var = s2 * (1.0f / DD) - mu * mu;
  float rsd = rsqrtf(var + 1e-3f);
  const float* g = gamma + j * 8;
  const float* bb = beta + j * 8;
  float* ob = out + base;
#pragma unroll
  for (int e = 0; e < 8; ++e) ob[e] = (v[e] - mu) * rsd * g[e] + bb[e];
}

// ---------------- launch ----------------
extern "C" void kernel_launch(void* const* d_in, const int* in_sizes, int n_in,
                              void* d_out, int out_size, void* d_ws, size_t ws_size,
                              hipStream_t stream) {
  (void)in_sizes; (void)n_in; (void)out_size; (void)ws_size;
  const float* queries = (const float*)d_in[0];
  const float* keys_in = (const float*)d_in[1];
  const float* Wq = (const float*)d_in[2];
  const float* bq = (const float*)d_in[3];
  const float* Wk = (const float*)d_in[4];
  const float* bk = (const float*)d_in[5];
  const float* Wv = (const float*)d_in[6];
  const float* bv = (const float*)d_in[7];
  const float* gamma = (const float*)d_in[8];
  const float* beta  = (const float*)d_in[9];
  float* out = (float*)d_out;

  char* ws = (char*)d_ws;
  unsigned short* qb = (unsigned short*)(ws);          // [0,8 MB)
  unsigned short* kb = (unsigned short*)(ws + (8ull << 20));
  unsigned short* Opart = (unsigned short*)(ws);       // aliases qb/kb after gemm (16 MB)
  unsigned short* Qp = (unsigned short*)(ws + (16ull << 20));
  unsigned short* Kp = (unsigned short*)(ws + (24ull << 20));
  unsigned short* Vp = (unsigned short*)(ws + (32ull << 20));
  unsigned short* Vt = (unsigned short*)(ws + (40ull << 20));
  unsigned short* Wt = (unsigned short*)(ws + (48ull << 20));
  float* qmaskp = (float*)(ws + (50ull << 20));
  uint2* kbitsp = (uint2*)(ws + (50ull << 20) + (512ull << 10));
  float2* mlp   = (float2*)(ws + (51ull << 20));       // 1 MB

  prep_kernel<<<4864, 256, 0, stream>>>((const float4*)queries, (const float4*)keys_in,
                                        (us4*)qb, (us4*)kb, Wq, Wk, Wv, Wt);
  gemm_proj<<<dim3(64, 4, 3), 256, 0, stream>>>(qb, kb, Wt, bq, bk, bv, Qp, Kp, Vp);
  post_proj<<<1536, 256, 0, stream>>>(Qp, Kp, Vp, Vt, qmaskp, kbitsp);
  attn_kernel<<<1024, 256, 0, stream>>>(Qp, Kp, Vt, kbitsp, Opart, mlp);
  ln_merge<<<2048, 256, 0, stream>>>(Opart, mlp, qmaskp, queries, gamma, beta, out);
}

// Round 7
// 203.004 us; speedup vs baseline: 1.0640x; 1.0201x over previous
//
#include <hip/hip_runtime.h>
#include <cstdint>

// Problem constants
#define BB 4
#define TT 2048      // TQ == TK
#define DD 512
#define HH 8
#define DH 64
#define NT (TT / 64) // KV tiles of 64
#define LOG2E 1.4426950408889634f

using bf16x8 = __attribute__((ext_vector_type(8))) __bf16;
using f32x4  = __attribute__((ext_vector_type(4))) float;
using f32x16 = __attribute__((ext_vector_type(16))) float;
using us8    = __attribute__((ext_vector_type(8))) unsigned short;
using us4    = __attribute__((ext_vector_type(4))) unsigned short;
using u32x2  = __attribute__((ext_vector_type(2))) unsigned int;

typedef const __attribute__((address_space(1))) unsigned int* as1cp;
typedef __attribute__((address_space(3))) unsigned int* as3p;

__device__ __forceinline__ void gload16(const void* g, void* l) {
  __builtin_amdgcn_global_load_lds((as1cp)(uintptr_t)g,
                                   (as3p)(unsigned int)(uintptr_t)l, 16, 0, 0);
}

__device__ __forceinline__ unsigned short f2bf(float x) {
  unsigned int u = __float_as_uint(x);
  u += 0x7fffu + ((u >> 16) & 1u);
  return (unsigned short)(u >> 16);
}
__device__ __forceinline__ float bf2f(unsigned short u) {
  return __uint_as_float(((unsigned int)u) << 16);
}
__device__ __forceinline__ f32x4 MFMA(bf16x8 a, bf16x8 b, f32x4 c) {
  return __builtin_amdgcn_mfma_f32_16x16x32_bf16(a, b, c, 0, 0, 0);
}
__device__ __forceinline__ f32x16 MFMA32(bf16x8 a, bf16x8 b, f32x16 c) {
  return __builtin_amdgcn_mfma_f32_32x32x16_bf16(a, b, c, 0, 0, 0);
}

#define WAITVM(N) asm volatile("s_waitcnt vmcnt(" #N ")" ::: "memory")
#define RAWBAR() asm volatile("s_barrier" ::: "memory")

// ---------------- 1. prep: convert inputs to bf16 + weight transpose ----------------
__global__ __launch_bounds__(256) void prep_kernel(const float4* __restrict__ q,
                                                   const float4* __restrict__ k,
                                                   us4* __restrict__ qb,
                                                   us4* __restrict__ kb,
                                                   const float* __restrict__ Wq,
                                                   const float* __restrict__ Wk,
                                                   const float* __restrict__ Wv,
                                                   unsigned short* __restrict__ Wt) {
  __shared__ float tile[32][33];
  int id = blockIdx.x;
  if (id < 4096) {
    size_t i = (size_t)id * 256 + threadIdx.x;
    float4 a = q[i];
    us4 o; o[0] = f2bf(a.x); o[1] = f2bf(a.y); o[2] = f2bf(a.z); o[3] = f2bf(a.w);
    qb[i] = o;
    float4 b = k[i];
    us4 p; p[0] = f2bf(b.x); p[1] = f2bf(b.y); p[2] = f2bf(b.z); p[3] = f2bf(b.w);
    kb[i] = p;
  } else {
    int id2 = id - 4096;
    int z = id2 >> 8, rem = id2 & 255;
    const float* W = (z == 0) ? Wq : (z == 1) ? Wk : Wv;
    int k0 = (rem & 15) * 32, n0 = (rem >> 4) * 32;
    int r = threadIdx.x >> 5, c = threadIdx.x & 31;
#pragma unroll
    for (int p = 0; p < 4; ++p)
      tile[r + p * 8][c] = W[(size_t)(k0 + r + p * 8) * DD + n0 + c];
    __syncthreads();
    unsigned short* o = Wt + (size_t)z * DD * DD;
#pragma unroll
    for (int p = 0; p < 4; ++p)
      o[(size_t)(n0 + r + p * 8) * DD + k0 + c] = f2bf(tile[c][r + p * 8]);
  }
}

// ---------------- 2. projection GEMM: out = relu(A @ W + b) [* 0.125*log2e for Q] ----------------
// 128x128 tile, BK=32, double-buffered LDS with counted vmcnt (2-phase T3/T4 minimum).
#define GSTAGE(kt2, pbuf)                                                    \
  {                                                                          \
    int t_ = threadIdx.x;                                                    \
    _Pragma("unroll")                                                        \
    for (int it_ = 0; it_ < 2; ++it_) {                                      \
      int c_ = t_ + it_ * 256;                                               \
      gload16(A  + (size_t)(mb + (c_ >> 2)) * DD + (kt2) * 32 + (c_ & 3) * 8,\
              &As[pbuf][(size_t)c_ * 8]);                                    \
      gload16(Bt + (size_t)(nb + (c_ >> 2)) * DD + (kt2) * 32 + (c_ & 3) * 8,\
              &Bs[pbuf][(size_t)c_ * 8]);                                    \
    }                                                                        \
  }

__global__ __launch_bounds__(256) void gemm_proj(const unsigned short* __restrict__ qb,
                                                 const unsigned short* __restrict__ kb,
                                                 const unsigned short* __restrict__ Wt,
                                                 const float* __restrict__ bq,
                                                 const float* __restrict__ bk,
                                                 const float* __restrict__ bv,
                                                 unsigned short* __restrict__ Qp,
                                                 unsigned short* __restrict__ Kp,
                                                 unsigned short* __restrict__ Vp) {
  int z = blockIdx.z;
  const unsigned short* A  = (z == 0) ? qb : kb;
  const unsigned short* Bt = Wt + (size_t)z * DD * DD;
  const float* bias = (z == 0) ? bq : (z == 1) ? bk : bv;
  unsigned short* out = (z == 0) ? Qp : (z == 1) ? Kp : Vp;
  const float osc = (z == 0) ? 0.125f * LOG2E : 1.0f;  // scores in log2 domain

  __shared__ __align__(16) unsigned short As[2][128 * 32];
  __shared__ __align__(16) unsigned short Bs[2][128 * 32];

  int mb = blockIdx.x * 128, nb = blockIdx.y * 128;
  int w = threadIdx.x >> 6, lane = threadIdx.x & 63;
  int l15 = lane & 15, lg = lane >> 4;
  int wr = (w >> 1) * 64, wc = (w & 1) * 64;

  f32x4 acc[4][4] = {};

  GSTAGE(0, 0);
  for (int kt = 0; kt < DD / 32; ++kt) {
    int pb2 = kt & 1;
    if (kt + 1 < DD / 32) {
      GSTAGE(kt + 1, pb2 ^ 1);
      WAITVM(4);            // this tile's 4 loads done; next tile's in flight
    } else {
      WAITVM(0);
    }
    RAWBAR();

    bf16x8 af[4], bf[4];
#pragma unroll
    for (int m = 0; m < 4; ++m)
      af[m] = *(const bf16x8*)&As[pb2][(wr + m * 16 + l15) * 32 + lg * 8];
#pragma unroll
    for (int n = 0; n < 4; ++n)
      bf[n] = *(const bf16x8*)&Bs[pb2][(wc + n * 16 + l15) * 32 + lg * 8];
#pragma unroll
    for (int m = 0; m < 4; ++m)
#pragma unroll
      for (int n = 0; n < 4; ++n)
        acc[m][n] = MFMA(af[m], bf[n], acc[m][n]);

    if (kt + 1 < DD / 32) RAWBAR();   // all waves done reading before re-stage
  }

#pragma unroll
  for (int m = 0; m < 4; ++m)
#pragma unroll
    for (int n = 0; n < 4; ++n)
#pragma unroll
      for (int i = 0; i < 4; ++i) {
        int row = mb + wr + m * 16 + lg * 4 + i;
        int col = nb + wc + n * 16 + l15;
        float v = acc[m][n][i] + bias[col];
        out[(size_t)row * DD + col] = f2bf(fmaxf(v, 0.f) * osc);
      }
}

// ---------------- 3. post-proj: V transpose + masks ----------------
__global__ __launch_bounds__(256) void post_proj(const unsigned short* __restrict__ Qp,
                                                 const unsigned short* __restrict__ Kp,
                                                 const unsigned short* __restrict__ Vp,
                                                 unsigned short* __restrict__ Vt,
                                                 float* __restrict__ qmask,
                                                 uint2* __restrict__ kbits) {
  __shared__ unsigned short tile[64][72];
  int id = blockIdx.x;
  if (id < 1024) {           // V transpose: Vp[B*TK, D] -> Vt[B, D, TK]
    int b = id >> 8, k0 = (id & 31) * 64, d0 = ((id >> 5) & 7) * 64;
    int t = threadIdx.x;
    int r = t >> 3, c8 = (t & 7) * 8;
#pragma unroll
    for (int p = 0; p < 2; ++p) {
      int row = r + p * 32;
      us8 v = *(const us8*)&Vp[(size_t)(b * TT + k0 + row) * DD + d0 + c8];
#pragma unroll
      for (int j = 0; j < 8; ++j) tile[row][c8 + j] = v[j];
    }
    __syncthreads();
#pragma unroll
    for (int p = 0; p < 2; ++p) {
      int dr = r + p * 32;
      us8 o;
#pragma unroll
      for (int j = 0; j < 8; ++j) o[j] = tile[c8 + j][dr];
      *(us8*)&Vt[((size_t)b * DD + d0 + dr) * TT + k0 + c8] = o;
    }
  } else {                   // masks
    int wid = (id - 1024) * 4 + (threadIdx.x >> 6);   // [0, 2048)
    int lane = threadIdx.x & 63;
    int side = wid >> 10;            // 0 = Q, 1 = K
    int rem = wid & 1023;
    int bh = rem >> 5, tl = rem & 31;
    int b = bh >> 3, h = bh & 7;
    const unsigned short* src =
        (side ? Kp : Qp) + ((size_t)(b * TT + tl * 64 + lane)) * DD + h * DH;
    float s = 0.f;
#pragma unroll
    for (int j = 0; j < 64; j += 8) {
      us8 v = *(const us8*)(src + j);
#pragma unroll
      for (int e = 0; e < 8; ++e) s += bf2f(v[e]);
    }
    if (side == 0) {
      qmask[(size_t)bh * TT + tl * 64 + lane] = (s > 0.f) ? 1.f : 0.f;
    } else {
      unsigned long long mb = __ballot(s > 0.f);
      if (lane == 0)
        kbits[bh * NT + tl] = make_uint2((unsigned int)mb, (unsigned int)(mb >> 32));
    }
  }
}

// ---------------- 4. flash attention (32q/wave, MFMA32, K bit-swap perm, direct pack) ----------------
// K rows staged with kpos bits 2,3 swapped -> s-reg r of sN holds score for
// actual kpos = 32N + 16(r>>3) + 8h2 + (r&7), which IS the PV B-frag order:
// pack = plain bf16 casts, zero cross-lane ops. O^T = MFMA32(Vt, P): col stays
// q -> m/l/alpha/qmask all lane-local. Grid 512, each block does all 32 tiles.
#define STAGE(tt, pbuf)                                                      \
  {                                                                          \
    int c0_ = threadIdx.x;                                                   \
    _Pragma("unroll")                                                        \
    for (int it_ = 0; it_ < 2; ++it_) {                                      \
      int c_ = c0_ + it_ * 256;                                              \
      int r_ = c_ >> 3, j_ = c_ & 7;                                         \
      int js_ = j_ ^ (r_ & 7);                                               \
      int kr_ = (r_ & ~12) | ((r_ & 4) << 1) | ((r_ & 8) >> 1);              \
      gload16(kg + (size_t)((tt) * 64 + kr_) * DD + js_ * 8,                 \
              &KsBuf[pbuf][(size_t)c_ * 8]);                                 \
      gload16(vg + (size_t)r_ * TT + (tt) * 64 + js_ * 8,                    \
              &VsBuf[pbuf][(size_t)c_ * 8]);                                 \
    }                                                                        \
  }

__global__ __launch_bounds__(256) void attn_kernel(
    const unsigned short* __restrict__ Qp,
    const unsigned short* __restrict__ Kp,
    const unsigned short* __restrict__ Vt,
    const uint2* __restrict__ kbits,
    const float* __restrict__ qmask,
    float* __restrict__ O) {
  __shared__ __align__(16) unsigned short KsBuf[2][64 * 64];
  __shared__ __align__(16) unsigned short VsBuf[2][64 * 64];

  const int w = threadIdx.x >> 6;
  const int lane = threadIdx.x & 63;
  const int l31 = lane & 31, h2 = lane >> 5;

  // XCD-bijective swizzle: 512 blocks -> each (b,h)'s 16 q-tiles on one XCD
  int flat = blockIdx.x;
  int wg = (flat & 7) * 64 + (flat >> 3);
  int qt = wg & 15, bh = wg >> 4;
  int h = bh & 7, b = bh >> 3;
  int q0 = qt * 128 + w * 32;

  const unsigned short* qbase =
      Qp + ((size_t)(b * TT + q0 + l31)) * DD + h * DH + h2 * 8;
  bf16x8 qf[4];
#pragma unroll
  for (int kd = 0; kd < 4; ++kd) qf[kd] = *(const bf16x8*)(qbase + kd * 16);

  const unsigned short* kg = Kp + ((size_t)b * TT) * DD + h * DH;
  const unsigned short* vg = Vt + ((size_t)(b * DD + h * DH)) * TT;
  const uint2* kb_ptr = kbits + (size_t)bh * NT;

  f32x16 oat0 = {}, oat1 = {};
  float m_i = -1e30f, l_i = 0.f;

  STAGE(0, 0);

  for (int t = 0; t < NT; ++t) {
    int pb = t & 1;
    if (t + 1 < NT) {
      STAGE(t + 1, pb ^ 1);
      WAITVM(4);          // tile t's 4 loads done; t+1's stay in flight
    } else {
      WAITVM(0);
    }
    RAWBAR();

    const unsigned short* ksb = &KsBuf[pb][0];
    const unsigned short* vsb = &VsBuf[pb][0];

    // K A-frags + V A-frags (V issued early: latency hides under QK+softmax)
    bf16x8 kf0[4], kf1[4], vf0[4], vf1[4];
#pragma unroll
    for (int kd = 0; kd < 4; ++kd) {
      int x = ((kd * 2 + h2) ^ (l31 & 7)) << 3;
      kf0[kd] = *(const bf16x8*)&ksb[l31 * 64 + x];
      kf1[kd] = *(const bf16x8*)&ksb[(32 + l31) * 64 + x];
      vf0[kd] = *(const bf16x8*)&vsb[l31 * 64 + x];
      vf1[kd] = *(const bf16x8*)&vsb[(32 + l31) * 64 + x];
    }

    // S^T = K . Q^T
    f32x16 s0 = {}, s1 = {};
    __builtin_amdgcn_s_setprio(1);
#pragma unroll
    for (int kd = 0; kd < 4; ++kd) s0 = MFMA32(kf0[kd], qf[kd], s0);
#pragma unroll
    for (int kd = 0; kd < 4; ++kd) s1 = MFMA32(kf1[kd], qf[kd], s1);
    __builtin_amdgcn_s_setprio(0);

    // key mask (fast path: all ones). actual kpos(reg r, sN) = 32N+16(r>>3)+8h2+(r&7)
    uint2 kw = kb_ptr[t];
    if ((kw.x & kw.y) != 0xffffffffu) {
#pragma unroll
      for (int r = 0; r < 16; ++r) {
        int sh = ((r >> 3) << 4) + (h2 << 3) + (r & 7);
        if (!((kw.x >> sh) & 1)) s0[r] = -1e30f;
        if (!((kw.y >> sh) & 1)) s1[r] = -1e30f;
      }
    }

    // row max over own 32, then cross-half (h2 pair) combine
    float x0 = fmaxf(fmaxf(fmaxf(s0[0], s0[1]), fmaxf(s0[2], s0[3])),
                     fmaxf(fmaxf(s0[4], s0[5]), fmaxf(s0[6], s0[7])));
    float x1 = fmaxf(fmaxf(fmaxf(s0[8], s0[9]), fmaxf(s0[10], s0[11])),
                     fmaxf(fmaxf(s0[12], s0[13]), fmaxf(s0[14], s0[15])));
    float x2 = fmaxf(fmaxf(fmaxf(s1[0], s1[1]), fmaxf(s1[2], s1[3])),
                     fmaxf(fmaxf(s1[4], s1[5]), fmaxf(s1[6], s1[7])));
    float x3 = fmaxf(fmaxf(fmaxf(s1[8], s1[9]), fmaxf(s1[10], s1[11])),
                     fmaxf(fmaxf(s1[12], s1[13]), fmaxf(s1[14], s1[15])));
    float pm = fmaxf(fmaxf(x0, x1), fmaxf(x2, x3));
    u32x2 sw = __builtin_amdgcn_permlane32_swap(__float_as_uint(pm),
                                                __float_as_uint(pm), false, false);
    pm = fmaxf(__uint_as_float(sw[0]), __uint_as_float(sw[1]));

    // defer-max (log2 units): rescale only when max grew by > 12
    if (__any(pm > m_i + 12.f)) {
      float mn = fmaxf(m_i, pm);
      float al = exp2f(m_i - mn);
      m_i = mn;
      l_i *= al;
#pragma unroll
      for (int r = 0; r < 16; ++r) { oat0[r] *= al; oat1[r] *= al; }
    }

    // p = exp2(s - m), row sum (4 accumulators)
    float a0 = 0.f, a1 = 0.f, a2 = 0.f, a3 = 0.f;
#pragma unroll
    for (int r = 0; r < 8; ++r)  { float p = exp2f(s0[r] - m_i); s0[r] = p; a0 += p; }
#pragma unroll
    for (int r = 8; r < 16; ++r) { float p = exp2f(s0[r] - m_i); s0[r] = p; a1 += p; }
#pragma unroll
    for (int r = 0; r < 8; ++r)  { float p = exp2f(s1[r] - m_i); s1[r] = p; a2 += p; }
#pragma unroll
    for (int r = 8; r < 16; ++r) { float p = exp2f(s1[r] - m_i); s1[r] = p; a3 += p; }
    float rs = (a0 + a1) + (a2 + a3);
    u32x2 sr = __builtin_amdgcn_permlane32_swap(__float_as_uint(rs),
                                                __float_as_uint(rs), false, false);
    rs = __uint_as_float(sr[0]) + __uint_as_float(sr[1]);
    l_i += rs;

    // P -> bf16 B-frags: direct per-lane concatenation (perm makes order exact)
    bf16x8 pbf[4];
#pragma unroll
    for (int j = 0; j < 8; ++j) {
      pbf[0][j] = (__bf16)s0[j];
      pbf[1][j] = (__bf16)s0[8 + j];
      pbf[2][j] = (__bf16)s1[j];
      pbf[3][j] = (__bf16)s1[8 + j];
    }

    // O^T += Vt . P
    __builtin_amdgcn_s_setprio(1);
#pragma unroll
    for (int ks = 0; ks < 4; ++ks) {
      oat0 = MFMA32(vf0[ks], pbf[ks], oat0);
      oat1 = MFMA32(vf1[ks], pbf[ks], oat1);
    }
    __builtin_amdgcn_s_setprio(0);

    if (t + 1 < NT) RAWBAR();   // all waves done reading buf[pb] before overwrite
  }

  // epilogue: lane(l31,h2) holds O[d=(r&3)+8*(r>>2)+4h2 (+32 for oat1)][q=q0+l31]
  float qm = qmask[(size_t)bh * TT + q0 + l31];
  float sc = qm / fmaxf(l_i, 1e-30f);
  float* ob = O + ((size_t)(b * TT + q0 + l31)) * DD + h * DH + h2 * 4;
#pragma unroll
  for (int qq = 0; qq < 4; ++qq) {
    float4 v0 = make_float4(oat0[4 * qq + 0] * sc, oat0[4 * qq + 1] * sc,
                            oat0[4 * qq + 2] * sc, oat0[4 * qq + 3] * sc);
    *(float4*)(ob + 8 * qq) = v0;
    float4 v1 = make_float4(oat1[4 * qq + 0] * sc, oat1[4 * qq + 1] * sc,
                            oat1[4 * qq + 2] * sc, oat1[4 * qq + 3] * sc);
    *(float4*)(ob + 32 + 8 * qq) = v1;
  }
}

// ---------------- 5. residual + LayerNorm ----------------
__global__ __launch_bounds__(256) void ln_kernel(const float* __restrict__ O,
                                                 const float* __restrict__ qin,
                                                 const float* __restrict__ gamma,
                                                 const float* __restrict__ beta,
                                                 float* __restrict__ out) {
  int row = blockIdx.x * 4 + (threadIdx.x >> 6);
  int lane = threadIdx.x & 63;
  size_t base = (size_t)row * DD + lane * 8;
  const float4* o4 = (const float4*)(O + base);
  const float4* q4 = (const float4*)(qin + base);
  float4 a = o4[0], b2 = o4[1], c = q4[0], d2 = q4[1];
  float v[8];
  v[0] = a.x + c.x; v[1] = a.y + c.y; v[2] = a.z + c.z; v[3] = a.w + c.w;
  v[4] = b2.x + d2.x; v[5] = b2.y + d2.y; v[6] = b2.z + d2.z; v[7] = b2.w + d2.w;
  float s = 0.f, s2 = 0.f;
#pragma unroll
  for (int j = 0; j < 8; ++j) { s += v[j]; s2 += v[j] * v[j]; }
#pragma unroll
  for (int xm = 1; xm < 64; xm <<= 1) {
    s += __shfl_xor(s, xm);
    s2 += __shfl_xor(s2, xm);
  }
  float mu = s * (1.0f / DD);
  float var = s2 * (1.0f / DD) - mu * mu;
  float rs = rsqrtf(var + 1e-3f);
  const float* g = gamma + lane * 8;
  const float* bb = beta + lane * 8;
  float* ob = out + base;
#pragma unroll
  for (int j = 0; j < 8; ++j) ob[j] = (v[j] - mu) * rs * g[j] + bb[j];
}

// ---------------- launch ----------------
extern "C" void kernel_launch(void* const* d_in, const int* in_sizes, int n_in,
                              void* d_out, int out_size, void* d_ws, size_t ws_size,
                              hipStream_t stream) {
  (void)in_sizes; (void)n_in; (void)out_size; (void)ws_size;
  const float* queries = (const float*)d_in[0];
  const float* keys_in = (const float*)d_in[1];
  const float* Wq = (const float*)d_in[2];
  const float* bq = (const float*)d_in[3];
  const float* Wk = (const float*)d_in[4];
  const float* bk = (const float*)d_in[5];
  const float* Wv = (const float*)d_in[6];
  const float* bv = (const float*)d_in[7];
  const float* gamma = (const float*)d_in[8];
  const float* beta  = (const float*)d_in[9];
  float* out = (float*)d_out;

  char* ws = (char*)d_ws;
  unsigned short* qb = (unsigned short*)(ws);          // [0,8 MB)
  unsigned short* kb = (unsigned short*)(ws + (8ull << 20));
  float*          O  = (float*)(ws);                   // aliases qb/kb after gemm
  unsigned short* Qp = (unsigned short*)(ws + (16ull << 20));
  unsigned short* Kp = (unsigned short*)(ws + (24ull << 20));
  unsigned short* Vp = (unsigned short*)(ws + (32ull << 20));
  unsigned short* Vt = (unsigned short*)(ws + (40ull << 20));
  unsigned short* Wt = (unsigned short*)(ws + (48ull << 20));
  float* qmaskp = (float*)(ws + (50ull << 20));
  uint2* kbitsp = (uint2*)(ws + (50ull << 20) + (512ull << 10));

  prep_kernel<<<4864, 256, 0, stream>>>((const float4*)queries, (const float4*)keys_in,
                                        (us4*)qb, (us4*)kb, Wq, Wk, Wv, Wt);
  gemm_proj<<<dim3(64, 4, 3), 256, 0, stream>>>(qb, kb, Wt, bq, bk, bv, Qp, Kp, Vp);
  post_proj<<<1536, 256, 0, stream>>>(Qp, Kp, Vp, Vt, qmaskp, kbitsp);
  attn_kernel<<<512, 256, 0, stream>>>(Qp, Kp, Vt, kbitsp, qmaskp, O);
  ln_kernel<<<2048, 256, 0, stream>>>(O, queries, gamma, beta, out);
}

// Round 8
// 192.845 us; speedup vs baseline: 1.1201x; 1.0527x over previous
//
#include <hip/hip_runtime.h>
#include <cstdint>

// Problem constants
#define BB 4
#define TT 2048      // TQ == TK
#define DD 512
#define HH 8
#define DH 64
#define NT (TT / 64) // KV tiles of 64
#define LOG2E 1.4426950408889634f

using bf16x8 = __attribute__((ext_vector_type(8))) __bf16;
using f32x4  = __attribute__((ext_vector_type(4))) float;
using f32x16 = __attribute__((ext_vector_type(16))) float;
using us8    = __attribute__((ext_vector_type(8))) unsigned short;
using us4    = __attribute__((ext_vector_type(4))) unsigned short;
using u32x2  = __attribute__((ext_vector_type(2))) unsigned int;

typedef const __attribute__((address_space(1))) unsigned int* as1cp;
typedef __attribute__((address_space(3))) unsigned int* as3p;

__device__ __forceinline__ void gload16(const void* g, void* l) {
  __builtin_amdgcn_global_load_lds((as1cp)(uintptr_t)g,
                                   (as3p)(unsigned int)(uintptr_t)l, 16, 0, 0);
}

__device__ __forceinline__ unsigned short f2bf(float x) {
  unsigned int u = __float_as_uint(x);
  u += 0x7fffu + ((u >> 16) & 1u);
  return (unsigned short)(u >> 16);
}
__device__ __forceinline__ float bf2f(unsigned short u) {
  return __uint_as_float(((unsigned int)u) << 16);
}
__device__ __forceinline__ f32x4 MFMA(bf16x8 a, bf16x8 b, f32x4 c) {
  return __builtin_amdgcn_mfma_f32_16x16x32_bf16(a, b, c, 0, 0, 0);
}
__device__ __forceinline__ f32x16 MFMA32(bf16x8 a, bf16x8 b, f32x16 c) {
  return __builtin_amdgcn_mfma_f32_32x32x16_bf16(a, b, c, 0, 0, 0);
}

#define WAITVM(N) asm volatile("s_waitcnt vmcnt(" #N ")" ::: "memory")
#define RAWBAR() asm volatile("s_barrier" ::: "memory")

// ---------------- 1. prep: convert inputs to bf16 + weight transpose ----------------
__global__ __launch_bounds__(256) void prep_kernel(const float4* __restrict__ q,
                                                   const float4* __restrict__ k,
                                                   us4* __restrict__ qb,
                                                   us4* __restrict__ kb,
                                                   const float* __restrict__ Wq,
                                                   const float* __restrict__ Wk,
                                                   const float* __restrict__ Wv,
                                                   unsigned short* __restrict__ Wt) {
  __shared__ float tile[32][33];
  int id = blockIdx.x;
  if (id < 4096) {
    size_t i = (size_t)id * 256 + threadIdx.x;
    float4 a = q[i];
    us4 o; o[0] = f2bf(a.x); o[1] = f2bf(a.y); o[2] = f2bf(a.z); o[3] = f2bf(a.w);
    qb[i] = o;
    float4 b = k[i];
    us4 p; p[0] = f2bf(b.x); p[1] = f2bf(b.y); p[2] = f2bf(b.z); p[3] = f2bf(b.w);
    kb[i] = p;
  } else {
    int id2 = id - 4096;
    int z = id2 >> 8, rem = id2 & 255;
    const float* W = (z == 0) ? Wq : (z == 1) ? Wk : Wv;
    int k0 = (rem & 15) * 32, n0 = (rem >> 4) * 32;
    int r = threadIdx.x >> 5, c = threadIdx.x & 31;
#pragma unroll
    for (int p = 0; p < 4; ++p)
      tile[r + p * 8][c] = W[(size_t)(k0 + r + p * 8) * DD + n0 + c];
    __syncthreads();
    unsigned short* o = Wt + (size_t)z * DD * DD;
#pragma unroll
    for (int p = 0; p < 4; ++p)
      o[(size_t)(n0 + r + p * 8) * DD + k0 + c] = f2bf(tile[c][r + p * 8]);
  }
}

// ---------------- 2. projection GEMM (r7 structure, 2-phase counted vmcnt) ----------------
#define GSTAGE(kt2, pbuf)                                                    \
  {                                                                          \
    int t_ = threadIdx.x;                                                    \
    _Pragma("unroll")                                                        \
    for (int it_ = 0; it_ < 2; ++it_) {                                      \
      int c_ = t_ + it_ * 256;                                               \
      gload16(A  + (size_t)(mb + (c_ >> 2)) * DD + (kt2) * 32 + (c_ & 3) * 8,\
              &As[pbuf][(size_t)c_ * 8]);                                    \
      gload16(Bt + (size_t)(nb + (c_ >> 2)) * DD + (kt2) * 32 + (c_ & 3) * 8,\
              &Bs[pbuf][(size_t)c_ * 8]);                                    \
    }                                                                        \
  }

__global__ __launch_bounds__(256) void gemm_proj(const unsigned short* __restrict__ qb,
                                                 const unsigned short* __restrict__ kb,
                                                 const unsigned short* __restrict__ Wt,
                                                 const float* __restrict__ bq,
                                                 const float* __restrict__ bk,
                                                 const float* __restrict__ bv,
                                                 unsigned short* __restrict__ Qp,
                                                 unsigned short* __restrict__ Kp,
                                                 unsigned short* __restrict__ Vp) {
  int z = blockIdx.z;
  const unsigned short* A  = (z == 0) ? qb : kb;
  const unsigned short* Bt = Wt + (size_t)z * DD * DD;
  const float* bias = (z == 0) ? bq : (z == 1) ? bk : bv;
  unsigned short* out = (z == 0) ? Qp : (z == 1) ? Kp : Vp;
  const float osc = (z == 0) ? 0.125f * LOG2E : 1.0f;  // scores in log2 domain

  __shared__ __align__(16) unsigned short As[2][128 * 32];
  __shared__ __align__(16) unsigned short Bs[2][128 * 32];

  int mb = blockIdx.x * 128, nb = blockIdx.y * 128;
  int w = threadIdx.x >> 6, lane = threadIdx.x & 63;
  int l15 = lane & 15, lg = lane >> 4;
  int wr = (w >> 1) * 64, wc = (w & 1) * 64;

  f32x4 acc[4][4] = {};

  GSTAGE(0, 0);
  for (int kt = 0; kt < DD / 32; ++kt) {
    int pb2 = kt & 1;
    if (kt + 1 < DD / 32) {
      GSTAGE(kt + 1, pb2 ^ 1);
      WAITVM(4);
    } else {
      WAITVM(0);
    }
    RAWBAR();

    bf16x8 af[4], bf[4];
#pragma unroll
    for (int m = 0; m < 4; ++m)
      af[m] = *(const bf16x8*)&As[pb2][(wr + m * 16 + l15) * 32 + lg * 8];
#pragma unroll
    for (int n = 0; n < 4; ++n)
      bf[n] = *(const bf16x8*)&Bs[pb2][(wc + n * 16 + l15) * 32 + lg * 8];
#pragma unroll
    for (int m = 0; m < 4; ++m)
#pragma unroll
      for (int n = 0; n < 4; ++n)
        acc[m][n] = MFMA(af[m], bf[n], acc[m][n]);

    if (kt + 1 < DD / 32) RAWBAR();
  }

#pragma unroll
  for (int m = 0; m < 4; ++m)
#pragma unroll
    for (int n = 0; n < 4; ++n)
#pragma unroll
      for (int i = 0; i < 4; ++i) {
        int row = mb + wr + m * 16 + lg * 4 + i;
        int col = nb + wc + n * 16 + l15;
        float v = acc[m][n][i] + bias[col];
        out[(size_t)row * DD + col] = f2bf(fmaxf(v, 0.f) * osc);
      }
}

// ---------------- 3. post-proj: build fragment-order Kpack/Vpack + masks ----------------
// Kpack content (tile t, half n, chunk kd, lane=(l31,h2)):
//   K[b][t*64 + 32n + bs(l31)][h*64 + kd*16 + h2*8 + j]   (bs = swap bits 2,3)
//   addr: (((bh*NT+t)*2+n)*4+kd)*512 + lane*8    -> attn loads are 16B/lane coalesced
// Vpack content (tile t, half, chunk ks, lane):
//   V[b][t*64 + ks*16 + h2*8 + j][h*64 + 32*half + l31]
//   addr: (((bh*NT+t)*2+half)*4+ks)*512 + lane*8
__global__ __launch_bounds__(256) void post_proj(const unsigned short* __restrict__ Qp,
                                                 const unsigned short* __restrict__ Kp,
                                                 const unsigned short* __restrict__ Vp,
                                                 unsigned short* __restrict__ Kpack,
                                                 unsigned short* __restrict__ Vpack,
                                                 float* __restrict__ qmask,
                                                 uint2* __restrict__ kbits) {
  __shared__ __align__(16) unsigned short tile[64 * 256];
  int id = blockIdx.x;
  int w = threadIdx.x >> 6, lane = threadIdx.x & 63;
  int l31 = lane & 31, h2 = lane >> 5;

  if (id < 256) {
    // ---- Vpack: block per (b, t, head-group of 4) ----
    int b = id >> 6, t = (id >> 1) & 31, hg = id & 1;
    {
      int c0 = threadIdx.x;
#pragma unroll
      for (int it = 0; it < 8; ++it) {
        int c = c0 + it * 256;
        int row = c >> 5, ch = c & 31;
        gload16(Vp + ((size_t)(b * TT + t * 64 + row)) * DD + hg * 256 + ch * 8,
                tile + (size_t)c * 8);
      }
    }
    __syncthreads();
#pragma unroll
    for (int cc = 0; cc < 8; ++cc) {
      int chunk = w * 8 + cc;                 // hh = w, half = cc>>2, ks = cc&3
      int hh = chunk >> 3, half = (cc >> 2) & 1, ks = cc & 3;
      us8 o;
#pragma unroll
      for (int j = 0; j < 8; ++j)
        o[j] = tile[(ks * 16 + h2 * 8 + j) * 256 + hh * 64 + half * 32 + l31];
      int bh = b * 8 + hg * 4 + hh;
      *(us8*)(Vpack + ((((size_t)bh * NT + t) * 2 + half) * 4 + ks) * 512 + lane * 8) = o;
    }
  } else if (id < 768) {
    // ---- Kpack: wave per (bh, t, n) ----
    int wid = (id - 256) * 4 + w;             // [0, 2048)
    int n = wid & 1, t = (wid >> 1) & 31, bh = wid >> 6;
    int b = bh >> 3, h = bh & 7;
    int bs = (l31 & ~12) | ((l31 & 4) << 1) | ((l31 & 8) >> 1);
    const unsigned short* src =
        Kp + ((size_t)(b * TT + t * 64 + 32 * n + bs)) * DD + h * DH + h2 * 8;
    unsigned short* dst = Kpack + (((size_t)bh * NT + t) * 2 + n) * 2048 + lane * 8;
#pragma unroll
    for (int kd = 0; kd < 4; ++kd)
      *(us8*)(dst + kd * 512) = *(const us8*)(src + kd * 16);
  } else {
    // ---- masks ----
    int wid = (id - 768) * 4 + w;             // [0, 2048)
    int side = wid >> 10;                     // 0 = Q, 1 = K
    int rem = wid & 1023;
    int bh = rem >> 5, tl = rem & 31;
    int b = bh >> 3, h = bh & 7;
    const unsigned short* src =
        (side ? Kp : Qp) + ((size_t)(b * TT + tl * 64 + lane)) * DD + h * DH;
    float s = 0.f;
#pragma unroll
    for (int j = 0; j < 64; j += 8) {
      us8 v = *(const us8*)(src + j);
#pragma unroll
      for (int e = 0; e < 8; ++e) s += bf2f(v[e]);
    }
    if (side == 0) {
      qmask[(size_t)bh * TT + tl * 64 + lane] = (s > 0.f) ? 1.f : 0.f;
    } else {
      unsigned long long mb = __ballot(s > 0.f);
      if (lane == 0)
        kbits[bh * NT + tl] = make_uint2((unsigned int)mb, (unsigned int)(mb >> 32));
    }
  }
}

// ---------------- 4. flash attention: NO LDS, no barriers, packed-fragment loads ----------------
// Per wave (32 q): S^T = MFMA32(Kfrag, Qfrag); score reg r of sN = kpos
// 32N+16(r>>3)+8h2+(r&7) (bit-swap packing) = PV B-frag order -> pack = plain casts.
// O^T = MFMA32(Vfrag, Pfrag): all softmax state lane-local. K reg-double-buffered.
__device__ __forceinline__ void attn_body(
    int t, int tp,
    const bf16x8 (&Kc)[8], bf16x8 (&Kn)[8], const bf16x8 (&qf)[4],
    f32x16& oat0, f32x16& oat1, float& m_i, float& l_i,
    const unsigned short* __restrict__ kgp, const unsigned short* __restrict__ vgp,
    const uint2* __restrict__ kb_ptr, int h2) {
  // QK^T
  f32x16 s0 = {}, s1 = {};
  __builtin_amdgcn_s_setprio(1);
#pragma unroll
  for (int kd = 0; kd < 4; ++kd) s0 = MFMA32(Kc[kd], qf[kd], s0);
#pragma unroll
  for (int kd = 0; kd < 4; ++kd) s1 = MFMA32(Kc[4 + kd], qf[kd], s1);
  __builtin_amdgcn_s_setprio(0);

  // prefetch next K tile (latency hides under softmax+PV of this tile)
  const unsigned short* kn = kgp + (size_t)tp * 4096;
#pragma unroll
  for (int c = 0; c < 8; ++c) Kn[c] = *(const bf16x8*)(kn + c * 512);

  // V for this tile (consumed after softmax ~300 cyc later)
  bf16x8 vc[8];
  const unsigned short* vp = vgp + (size_t)t * 4096;
#pragma unroll
  for (int c = 0; c < 8; ++c) vc[c] = *(const bf16x8*)(vp + c * 512);

  // key mask (fast path: all ones). kpos(reg r, sN) = 32N+16(r>>3)+8h2+(r&7)
  uint2 kw = kb_ptr[t];
  if ((kw.x & kw.y) != 0xffffffffu) {
#pragma unroll
    for (int r = 0; r < 16; ++r) {
      int sh = ((r >> 3) << 4) + (h2 << 3) + (r & 7);
      if (!((kw.x >> sh) & 1)) s0[r] = -1e30f;
      if (!((kw.y >> sh) & 1)) s1[r] = -1e30f;
    }
  }

  // row max over own 32, then cross-half combine
  float x0 = fmaxf(fmaxf(fmaxf(s0[0], s0[1]), fmaxf(s0[2], s0[3])),
                   fmaxf(fmaxf(s0[4], s0[5]), fmaxf(s0[6], s0[7])));
  float x1 = fmaxf(fmaxf(fmaxf(s0[8], s0[9]), fmaxf(s0[10], s0[11])),
                   fmaxf(fmaxf(s0[12], s0[13]), fmaxf(s0[14], s0[15])));
  float x2 = fmaxf(fmaxf(fmaxf(s1[0], s1[1]), fmaxf(s1[2], s1[3])),
                   fmaxf(fmaxf(s1[4], s1[5]), fmaxf(s1[6], s1[7])));
  float x3 = fmaxf(fmaxf(fmaxf(s1[8], s1[9]), fmaxf(s1[10], s1[11])),
                   fmaxf(fmaxf(s1[12], s1[13]), fmaxf(s1[14], s1[15])));
  float pm = fmaxf(fmaxf(x0, x1), fmaxf(x2, x3));
  u32x2 sw = __builtin_amdgcn_permlane32_swap(__float_as_uint(pm),
                                              __float_as_uint(pm), false, false);
  pm = fmaxf(__uint_as_float(sw[0]), __uint_as_float(sw[1]));

  // defer-max (log2 units)
  if (__any(pm > m_i + 12.f)) {
    float mn = fmaxf(m_i, pm);
    float al = exp2f(m_i - mn);
    m_i = mn;
    l_i *= al;
#pragma unroll
    for (int r = 0; r < 16; ++r) { oat0[r] *= al; oat1[r] *= al; }
  }

  // p = exp2(s - m), row sum
  float a0 = 0.f, a1 = 0.f, a2 = 0.f, a3 = 0.f;
#pragma unroll
  for (int r = 0; r < 8; ++r)  { float p = exp2f(s0[r] - m_i); s0[r] = p; a0 += p; }
#pragma unroll
  for (int r = 8; r < 16; ++r) { float p = exp2f(s0[r] - m_i); s0[r] = p; a1 += p; }
#pragma unroll
  for (int r = 0; r < 8; ++r)  { float p = exp2f(s1[r] - m_i); s1[r] = p; a2 += p; }
#pragma unroll
  for (int r = 8; r < 16; ++r) { float p = exp2f(s1[r] - m_i); s1[r] = p; a3 += p; }
  float rs = (a0 + a1) + (a2 + a3);
  u32x2 sr = __builtin_amdgcn_permlane32_swap(__float_as_uint(rs),
                                              __float_as_uint(rs), false, false);
  rs = __uint_as_float(sr[0]) + __uint_as_float(sr[1]);
  l_i += rs;

  // P -> bf16 B-frags (direct order by construction)
  bf16x8 pbf[4];
#pragma unroll
  for (int j = 0; j < 8; ++j) {
    pbf[0][j] = (__bf16)s0[j];
    pbf[1][j] = (__bf16)s0[8 + j];
    pbf[2][j] = (__bf16)s1[j];
    pbf[3][j] = (__bf16)s1[8 + j];
  }

  // O^T += V . P
  __builtin_amdgcn_s_setprio(1);
#pragma unroll
  for (int ks = 0; ks < 4; ++ks) {
    oat0 = MFMA32(vc[ks], pbf[ks], oat0);
    oat1 = MFMA32(vc[4 + ks], pbf[ks], oat1);
  }
  __builtin_amdgcn_s_setprio(0);
}

__global__ __launch_bounds__(256) void attn_kernel(
    const unsigned short* __restrict__ Qp,
    const unsigned short* __restrict__ Kpack,
    const unsigned short* __restrict__ Vpack,
    const uint2* __restrict__ kbits,
    const float* __restrict__ qmask,
    unsigned short* __restrict__ O) {          // bf16 output
  const int w = threadIdx.x >> 6;
  const int lane = threadIdx.x & 63;
  const int l31 = lane & 31, h2 = lane >> 5;

  // XCD-bijective swizzle: each XCD gets 4 (b,h) pairs (2 MB pack data -> L2)
  int flat = blockIdx.x;
  int wg = (flat & 7) * 64 + (flat >> 3);
  int qt = wg & 15, bh = wg >> 4;
  int h = bh & 7, b = bh >> 3;
  int q0 = qt * 128 + w * 32;

  const unsigned short* qbase =
      Qp + ((size_t)(b * TT + q0 + l31)) * DD + h * DH + h2 * 8;
  bf16x8 qf[4];
#pragma unroll
  for (int kd = 0; kd < 4; ++kd) qf[kd] = *(const bf16x8*)(qbase + kd * 16);

  const unsigned short* kgp = Kpack + (size_t)bh * NT * 4096 + lane * 8;
  const unsigned short* vgp = Vpack + (size_t)bh * NT * 4096 + lane * 8;
  const uint2* kb_ptr = kbits + (size_t)bh * NT;

  f32x16 oat0 = {}, oat1 = {};
  float m_i = -1e30f, l_i = 0.f;

  bf16x8 kA[8], kB[8];
#pragma unroll
  for (int c = 0; c < 8; ++c) kA[c] = *(const bf16x8*)(kgp + c * 512);

  for (int t = 0; t < NT; t += 2) {
    attn_body(t, t + 1, kA, kB, qf, oat0, oat1, m_i, l_i, kgp, vgp, kb_ptr, h2);
    attn_body(t + 1, (t + 2 < NT) ? t + 2 : 0, kB, kA, qf, oat0, oat1, m_i, l_i,
              kgp, vgp, kb_ptr, h2);
  }

  // epilogue: lane(l31,h2) holds O[d=(r&3)+8*(r>>2)+4h2 (+32 for oat1)][q=q0+l31]
  float qm = qmask[(size_t)bh * TT + q0 + l31];
  float sc = qm / fmaxf(l_i, 1e-30f);
  unsigned short* ob = O + ((size_t)(b * TT + q0 + l31)) * DD + h * DH + h2 * 4;
#pragma unroll
  for (int qq = 0; qq < 4; ++qq) {
    us4 w0, w1;
#pragma unroll
    for (int i = 0; i < 4; ++i) {
      w0[i] = f2bf(oat0[4 * qq + i] * sc);
      w1[i] = f2bf(oat1[4 * qq + i] * sc);
    }
    *(us4*)(ob + 8 * qq) = w0;
    *(us4*)(ob + 32 + 8 * qq) = w1;
  }
}

// ---------------- 5. residual + LayerNorm (O in bf16) ----------------
__global__ __launch_bounds__(256) void ln_kernel(const unsigned short* __restrict__ O,
                                                 const float* __restrict__ qin,
                                                 const float* __restrict__ gamma,
                                                 const float* __restrict__ beta,
                                                 float* __restrict__ out) {
  int row = blockIdx.x * 4 + (threadIdx.x >> 6);
  int lane = threadIdx.x & 63;
  size_t base = (size_t)row * DD + lane * 8;
  us8 o = *(const us8*)(O + base);
  const float4* q4 = (const float4*)(qin + base);
  float4 c = q4[0], d2 = q4[1];
  float qv[8] = {c.x, c.y, c.z, c.w, d2.x, d2.y, d2.z, d2.w};
  float v[8];
#pragma unroll
  for (int j = 0; j < 8; ++j) v[j] = bf2f(o[j]) + qv[j];
  float s = 0.f, s2 = 0.f;
#pragma unroll
  for (int j = 0; j < 8; ++j) { s += v[j]; s2 += v[j] * v[j]; }
#pragma unroll
  for (int xm = 1; xm < 64; xm <<= 1) {
    s += __shfl_xor(s, xm);
    s2 += __shfl_xor(s2, xm);
  }
  float mu = s * (1.0f / DD);
  float var = s2 * (1.0f / DD) - mu * mu;
  float rs = rsqrtf(var + 1e-3f);
  const float* g = gamma + lane * 8;
  const float* bb = beta + lane * 8;
  float* ob = out + base;
#pragma unroll
  for (int j = 0; j < 8; ++j) ob[j] = (v[j] - mu) * rs * g[j] + bb[j];
}

// ---------------- launch ----------------
extern "C" void kernel_launch(void* const* d_in, const int* in_sizes, int n_in,
                              void* d_out, int out_size, void* d_ws, size_t ws_size,
                              hipStream_t stream) {
  (void)in_sizes; (void)n_in; (void)out_size; (void)ws_size;
  const float* queries = (const float*)d_in[0];
  const float* keys_in = (const float*)d_in[1];
  const float* Wq = (const float*)d_in[2];
  const float* bq = (const float*)d_in[3];
  const float* Wk = (const float*)d_in[4];
  const float* bk = (const float*)d_in[5];
  const float* Wv = (const float*)d_in[6];
  const float* bv = (const float*)d_in[7];
  const float* gamma = (const float*)d_in[8];
  const float* beta  = (const float*)d_in[9];
  float* out = (float*)d_out;

  char* ws = (char*)d_ws;
  unsigned short* qb = (unsigned short*)(ws);            // [0,8 MB)   dead after gemm
  unsigned short* kb = (unsigned short*)(ws + (8ull << 20));  // [8,16) dead after gemm
  unsigned short* Obf   = (unsigned short*)(ws);         // bf16 O, aliases qb
  unsigned short* Vpack = (unsigned short*)(ws + (8ull << 20));   // aliases kb
  unsigned short* Qp = (unsigned short*)(ws + (16ull << 20));
  unsigned short* Kp = (unsigned short*)(ws + (24ull << 20));
  unsigned short* Vp = (unsigned short*)(ws + (32ull << 20));
  unsigned short* Kpack = (unsigned short*)(ws + (40ull << 20));
  unsigned short* Wt = (unsigned short*)(ws + (48ull << 20));
  float* qmaskp = (float*)(ws + (50ull << 20));
  uint2* kbitsp = (uint2*)(ws + (50ull << 20) + (512ull << 10));

  prep_kernel<<<4864, 256, 0, stream>>>((const float4*)queries, (const float4*)keys_in,
                                        (us4*)qb, (us4*)kb, Wq, Wk, Wv, Wt);
  gemm_proj<<<dim3(64, 4, 3), 256, 0, stream>>>(qb, kb, Wt, bq, bk, bv, Qp, Kp, Vp);
  post_proj<<<1280, 256, 0, stream>>>(Qp, Kp, Vp, Kpack, Vpack, qmaskp, kbitsp);
  attn_kernel<<<512, 256, 0, stream>>>(Qp, Kpack, Vpack, kbitsp, qmaskp, Obf);
  ln_kernel<<<2048, 256, 0, stream>>>(Obf, queries, gamma, beta, out);
}